// Round 5
// baseline (336.300 us; speedup 1.0000x reference)
//
#include <hip/hip_runtime.h>
#include <float.h>
#include <math.h>

#define NPTS  16384
#define HDIM  256
#define GRID  256                 // cells per axis
#define NCELL (GRID * GRID)
#define CELLW 0.390625f           // 100/256
#define INVCW 2.56f
#define XOFF  128.0f              // index = floor(x*INVCW + XOFF)

__device__ __forceinline__ float silu_f(float z) {
    return z / (1.0f + __expf(-z));
}

__device__ __forceinline__ int cell_idx(float v) {
    int i = (int)floorf(fmaf(v, INVCW, XOFF));
    return min(GRID - 1, max(0, i));
}

// ws layout (bytes) ------------------------------------------------------
// md      @ 0        : 16384 f
// counts  @ 65536    : 65536 i
// offsets @ 327680   : 65537 i (pad)
// cursor  @ 589840   : 65536 i
// bsum    @ 851984   : 64 i
// bpre    @ 852240   : 64 i
// spts    @ 852496   : 16384 float2
// nstrag  @ 983568   : 1 i
// strag   @ 983572   : 16384 i
#define WS_MD      0
#define WS_COUNTS  65536
#define WS_OFFSETS 327680
#define WS_CURSOR  589840
#define WS_BSUM    851984
#define WS_BPRE    852240
#define WS_SPTS    852496
#define WS_NSTRAG  983568
#define WS_STRAG   983572

// --- grid build ---------------------------------------------------------
__global__ void k_zero(int* counts, int* nstrag) {
    const int g = blockIdx.x * 256 + threadIdx.x;      // 64x256 -> 16384
    ((int4*)counts)[g] = make_int4(0, 0, 0, 0);        // 65536 ints
    if (g == 0) *nstrag = 0;
}

__global__ void k_hist(const float* __restrict__ xyf, int* counts) {
    const int i = blockIdx.x * 256 + threadIdx.x;      // 16384
    const float2 p = ((const float2*)xyf)[i];
    const int c = cell_idx(p.y) * GRID + cell_idx(p.x);
    atomicAdd(&counts[c], 1);
}

// block b scans counts[b*1024 .. +1024) -> per-element exclusive offsets
__global__ __launch_bounds__(256) void k_scanA(const int* __restrict__ counts,
                                               int* offsets, int* bsum) {
    __shared__ int sdata[256];
    const int tid = threadIdx.x;
    const int g   = blockIdx.x * 256 + tid;
    const int4 c4 = ((const int4*)counts)[g];
    const int tsum = c4.x + c4.y + c4.z + c4.w;
    sdata[tid] = tsum;
    __syncthreads();
    for (int off = 1; off < 256; off <<= 1) {
        int v = 0;
        if (tid >= off) v = sdata[tid - off];
        __syncthreads();
        sdata[tid] += v;
        __syncthreads();
    }
    int ex = sdata[tid] - tsum;                        // exclusive within block
    ((int4*)offsets)[g] = make_int4(ex, ex + c4.x, ex + c4.x + c4.y,
                                    ex + c4.x + c4.y + c4.z);
    if (tid == 255) bsum[blockIdx.x] = sdata[255];
}

__global__ void k_scanB(const int* __restrict__ bsum, int* bpre, int* offsets) {
    const int t = threadIdx.x;                         // 64 threads = 1 wave
    const int orig = bsum[t];
    int x = orig;
    for (int off = 1; off < 64; off <<= 1) {
        int y = __shfl_up(x, off, 64);
        if (t >= off) x += y;
    }
    bpre[t] = x - orig;
    if (t == 63) offsets[NCELL] = NPTS;
}

__global__ __launch_bounds__(256) void k_scanC(int* offsets, int* cursor,
                                               const int* __restrict__ bpre) {
    const int g = blockIdx.x * 256 + threadIdx.x;
    const int add = bpre[blockIdx.x];
    int4 o = ((int4*)offsets)[g];
    o.x += add; o.y += add; o.z += add; o.w += add;
    ((int4*)offsets)[g] = o;
    ((int4*)cursor)[g]  = o;
}

__global__ void k_scatter(const float* __restrict__ xyf, int* cursor,
                          float2* spts) {
    const int i = blockIdx.x * 256 + threadIdx.x;      // 16384
    const float2 p = ((const float2*)xyf)[i];
    const int c = cell_idx(p.y) * GRID + cell_idx(p.x);
    const int pos = atomicAdd(&cursor[c], 1);
    spts[pos] = p;
}

// --- phase A: per-thread expanding ring search, exact termination -------
__global__ void k_knnA(const float* __restrict__ xyf,
                       const int* __restrict__ offsets,
                       const float2* __restrict__ spts,
                       float* md, int* nstrag, int* strag) {
    const int i = blockIdx.x * 64 + threadIdx.x;       // 256 x 64 = 16384
    const float2 q = ((const float2*)xyf)[i];
    const int cx = cell_idx(q.x), cy = cell_idx(q.y);

    float s0 = FLT_MAX, s1 = FLT_MAX, s2 = FLT_MAX, s3 = FLT_MAX,
          s4 = FLT_MAX, s5 = FLT_MAX, s6 = FLT_MAX;
    bool done = false;

    for (int R = 0; R <= 3 && !done; ++R) {
        const int xlo = cx - R, xhi = cx + R, ylo = cy - R, yhi = cy + R;
        for (int iy = max(ylo, 0); iy <= min(yhi, GRID - 1); ++iy) {
            const bool edgeRow = (iy == ylo || iy == yhi);
            const int ix0 = edgeRow ? max(xlo, 0) : xlo;
            const int ix1 = edgeRow ? min(xhi, GRID - 1) : xhi;
            const int step = edgeRow ? 1 : (xhi - xlo > 0 ? xhi - xlo : 1);
            for (int ix = ix0; ix <= ix1; ix += step) {
                if (ix < 0 || ix > GRID - 1) continue;
                const int c  = iy * GRID + ix;
                const int st = offsets[c], en = offsets[c + 1];
                for (int p = st; p < en; ++p) {
                    const float2 pt = spts[p];
                    const float dx = q.x - pt.x, dy = q.y - pt.y;
                    const float d = fmaf(dx, dx, dy * dy);
                    if (d < s6) {
                        s6 = d; float t;
                        if (s6 < s5) { t = s5; s5 = s6; s6 = t; }
                        if (s5 < s4) { t = s4; s4 = s5; s5 = t; }
                        if (s4 < s3) { t = s3; s3 = s4; s4 = t; }
                        if (s3 < s2) { t = s2; s2 = s3; s3 = t; }
                        if (s2 < s1) { t = s1; s1 = s2; s2 = t; }
                        if (s1 < s0) { t = s0; s0 = s1; s1 = t; }
                    }
                }
            }
        }
        // exact bound: unseen points lie outside visited rect [xlo,xhi]x[ylo,yhi]
        const float bl = (xlo <= 0)        ? FLT_MAX : q.x - (xlo - XOFF) * CELLW;
        const float br = (xhi >= GRID - 1) ? FLT_MAX : (xhi + 1 - XOFF) * CELLW - q.x;
        const float bb = (ylo <= 0)        ? FLT_MAX : q.y - (ylo - XOFF) * CELLW;
        const float bt = (yhi >= GRID - 1) ? FLT_MAX : (yhi + 1 - XOFF) * CELLW - q.y;
        const float b = fminf(fminf(bl, br), fminf(bb, bt));
        if (s6 <= b * b) done = true;
    }

    if (done) {
        const float sum = sqrtf(fmaxf(s1, 1e-12f)) + sqrtf(fmaxf(s2, 1e-12f)) +
                          sqrtf(fmaxf(s3, 1e-12f)) + sqrtf(fmaxf(s4, 1e-12f)) +
                          sqrtf(fmaxf(s5, 1e-12f)) + sqrtf(fmaxf(s6, 1e-12f));
        md[i] = sum * (1.0f / 6.0f);
    } else {
        const int pos = atomicAdd(nstrag, 1);
        strag[pos] = i;
    }
}

// --- phase B: wave-per-query brute force for stragglers -----------------
__global__ __launch_bounds__(256) void k_knnB(const float* __restrict__ xyf,
                                              const int* __restrict__ nstrag,
                                              const int* __restrict__ strag,
                                              float* md) {
    const int lane = threadIdx.x & 63;
    const int wid  = blockIdx.x * 4 + (threadIdx.x >> 6);
    const int nw   = gridDim.x * 4;
    const int n    = *nstrag;
    const float4* xy4 = (const float4*)xyf;
    const float2* xy2 = (const float2*)xyf;

    for (int j = wid; j < n; j += nw) {
        const int qi = strag[j];
        const float2 q = xy2[qi];
        float t0 = FLT_MAX, t1 = FLT_MAX, t2 = FLT_MAX, t3 = FLT_MAX,
              t4 = FLT_MAX, t5 = FLT_MAX, t6 = FLT_MAX;
        for (int it = 0; it < NPTS / 2 / 64; ++it) {
            const float4 P = xy4[it * 64 + lane];
            float dx, dy, d;
            #pragma unroll
            for (int h = 0; h < 2; ++h) {
                dx = q.x - (h ? P.z : P.x);
                dy = q.y - (h ? P.w : P.y);
                d  = fmaf(dx, dx, dy * dy);
                if (d < t6) {
                    t6 = d; float t;
                    if (t6 < t5) { t = t5; t5 = t6; t6 = t; }
                    if (t5 < t4) { t = t4; t4 = t5; t5 = t; }
                    if (t4 < t3) { t = t3; t3 = t4; t4 = t; }
                    if (t3 < t2) { t = t2; t2 = t3; t3 = t; }
                    if (t2 < t1) { t = t1; t1 = t2; t2 = t; }
                    if (t1 < t0) { t = t0; t0 = t1; t1 = t; }
                }
            }
        }
        // merge 64 sorted lists: pop global min 7 times (round-1 verified)
        float sum = 0.0f;
        #pragma unroll
        for (int r = 0; r < 7; ++r) {
            const float v = t0;
            float m = v;
            #pragma unroll
            for (int o = 32; o; o >>= 1) m = fminf(m, __shfl_xor(m, o, 64));
            const unsigned long long msk = __ballot(v == m);
            if (lane == (__ffsll(msk) - 1)) {
                t0 = t1; t1 = t2; t2 = t3; t3 = t4; t4 = t5; t5 = t6;
                t6 = FLT_MAX;
            }
            if (r > 0) sum += sqrtf(fmaxf(m, 1e-12f));
        }
        if (lane == 0) md[qi] = sum * (1.0f / 6.0f);
    }
}

// --- fused MLP ----------------------------------------------------------
// 8 points x 256 cols per block, 2048 blocks -> 8 blocks/CU, 8 waves/SIMD.
// h1 stored [p][k] (lane-contiguous writes, wave-uniform broadcast reads);
// W2/Wd2 row loads: depth-4 prefetch ring.
__global__ __launch_bounds__(256, 8) void mlp_kernel(
        const float* __restrict__ xyf,
        const float* __restrict__ W1,  const float* __restrict__ b1,
        const float* __restrict__ W2,  const float* __restrict__ b2,
        const float* __restrict__ Wd1, const float* __restrict__ bd1,
        const float* __restrict__ Wd2, const float* __restrict__ bd2,
        const float* __restrict__ md,  float* __restrict__ out) {
    __shared__ float hA[8 * 260];
    __shared__ float hD[8 * 132];
    __shared__ float2 sxy[8];
    __shared__ float  smd[8];

    const int tid   = threadIdx.x;
    const int pbase = blockIdx.x * 8;

    if (tid < 8) {
        sxy[tid] = ((const float2*)xyf)[pbase + tid];
        smd[tid] = md[pbase + tid];
    }
    __syncthreads();

    {   // h1[p][k] = silu(x[p] @ W1[:,k] + b1[k]),  k = tid
        const float w0 = W1[tid], w1 = W1[HDIM + tid], b = b1[tid];
        #pragma unroll
        for (int p = 0; p < 8; ++p) {
            const float2 xp = sxy[p];
            hA[p * 260 + tid] = silu_f(fmaf(xp.x, w0, fmaf(xp.y, w1, b)));
        }
        if (tid < 128) {   // g[p][j] = silu(md[p]*Wd1[j] + bd1[j]), j = tid
            const float wd = Wd1[tid], bd = bd1[tid];
            #pragma unroll
            for (int p = 0; p < 8; ++p)
                hD[p * 132 + tid] = silu_f(fmaf(smd[p], wd, bd));
        }
    }
    __syncthreads();

    const int tx = tid & 63;
    const int ty = tid >> 6;
    const int c0 = tx * 4;
    const int p0 = ty * 2;

    float acc[2][4];
    #pragma unroll
    for (int p = 0; p < 2; ++p)
        #pragma unroll
        for (int c = 0; c < 4; ++c) acc[p][c] = 0.0f;

    {   // acc += h1 @ W2 ; depth-4 prefetch ring
        const float* Wc = W2 + c0;
        float4 w[4];
        #pragma unroll
        for (int i = 0; i < 4; ++i) w[i] = *(const float4*)(Wc + i * HDIM);
        #pragma unroll 4
        for (int k = 0; k < 256; ++k) {
            const float4 wk = w[k & 3];
            const int kp = min(k + 4, 255);
            w[k & 3] = *(const float4*)(Wc + kp * HDIM);
            const float a0 = hA[(p0 + 0) * 260 + k];
            const float a1 = hA[(p0 + 1) * 260 + k];
            acc[0][0] = fmaf(a0, wk.x, acc[0][0]);
            acc[0][1] = fmaf(a0, wk.y, acc[0][1]);
            acc[0][2] = fmaf(a0, wk.z, acc[0][2]);
            acc[0][3] = fmaf(a0, wk.w, acc[0][3]);
            acc[1][0] = fmaf(a1, wk.x, acc[1][0]);
            acc[1][1] = fmaf(a1, wk.y, acc[1][1]);
            acc[1][2] = fmaf(a1, wk.z, acc[1][2]);
            acc[1][3] = fmaf(a1, wk.w, acc[1][3]);
        }
    }
    {   // acc += g @ Wd2 ; depth-4 prefetch ring
        const float* Wc = Wd2 + c0;
        float4 w[4];
        #pragma unroll
        for (int i = 0; i < 4; ++i) w[i] = *(const float4*)(Wc + i * HDIM);
        #pragma unroll 4
        for (int k = 0; k < 128; ++k) {
            const float4 wk = w[k & 3];
            const int kp = min(k + 4, 127);
            w[k & 3] = *(const float4*)(Wc + kp * HDIM);
            const float a0 = hD[(p0 + 0) * 132 + k];
            const float a1 = hD[(p0 + 1) * 132 + k];
            acc[0][0] = fmaf(a0, wk.x, acc[0][0]);
            acc[0][1] = fmaf(a0, wk.y, acc[0][1]);
            acc[0][2] = fmaf(a0, wk.z, acc[0][2]);
            acc[0][3] = fmaf(a0, wk.w, acc[0][3]);
            acc[1][0] = fmaf(a1, wk.x, acc[1][0]);
            acc[1][1] = fmaf(a1, wk.y, acc[1][1]);
            acc[1][2] = fmaf(a1, wk.z, acc[1][2]);
            acc[1][3] = fmaf(a1, wk.w, acc[1][3]);
        }
    }

    const float4 v2 = *(const float4*)(b2 + c0);
    const float4 vd = *(const float4*)(bd2 + c0);
    #pragma unroll
    for (int p = 0; p < 2; ++p) {
        float4 o;
        o.x = acc[p][0] + v2.x + vd.x;
        o.y = acc[p][1] + v2.y + vd.y;
        o.z = acc[p][2] + v2.z + vd.z;
        o.w = acc[p][3] + v2.w + vd.w;
        *(float4*)(out + (size_t)(pbase + p0 + p) * HDIM + c0) = o;
    }
}

extern "C" void kernel_launch(void* const* d_in, const int* in_sizes, int n_in,
                              void* d_out, int out_size, void* d_ws, size_t ws_size,
                              hipStream_t stream) {
    const float* xy  = (const float*)d_in[0];
    const float* W1  = (const float*)d_in[1];
    const float* b1  = (const float*)d_in[2];
    const float* W2  = (const float*)d_in[3];
    const float* b2  = (const float*)d_in[4];
    const float* Wd1 = (const float*)d_in[5];
    const float* bd1 = (const float*)d_in[6];
    const float* Wd2 = (const float*)d_in[7];
    const float* bd2 = (const float*)d_in[8];
    float* out = (float*)d_out;

    char* ws = (char*)d_ws;
    float*  md      = (float*)(ws + WS_MD);
    int*    counts  = (int*)(ws + WS_COUNTS);
    int*    offsets = (int*)(ws + WS_OFFSETS);
    int*    cursor  = (int*)(ws + WS_CURSOR);
    int*    bsum    = (int*)(ws + WS_BSUM);
    int*    bpre    = (int*)(ws + WS_BPRE);
    float2* spts    = (float2*)(ws + WS_SPTS);
    int*    nstrag  = (int*)(ws + WS_NSTRAG);
    int*    strag   = (int*)(ws + WS_STRAG);

    k_zero   <<<64, 256, 0, stream>>>(counts, nstrag);
    k_hist   <<<64, 256, 0, stream>>>(xy, counts);
    k_scanA  <<<64, 256, 0, stream>>>(counts, offsets, bsum);
    k_scanB  <<<1, 64, 0, stream>>>(bsum, bpre, offsets);
    k_scanC  <<<64, 256, 0, stream>>>(offsets, cursor, bpre);
    k_scatter<<<64, 256, 0, stream>>>(xy, cursor, spts);
    k_knnA   <<<256, 64, 0, stream>>>(xy, offsets, spts, md, nstrag, strag);
    k_knnB   <<<256, 256, 0, stream>>>(xy, nstrag, strag, md);
    mlp_kernel<<<NPTS / 8, 256, 0, stream>>>(xy, W1, b1, W2, b2,
                                             Wd1, bd1, Wd2, bd2, md, out);
}

// Round 6
// 262.214 us; speedup vs baseline: 1.2825x; 1.2825x over previous
//
#include <hip/hip_runtime.h>
#include <float.h>
#include <math.h>

#define NPTS  16384
#define HDIM  256
#define GRID  256                 // cells per axis
#define NCELL (GRID * GRID)
#define CELLW 0.390625f           // 100/256
#define INVCW 2.56f
#define XOFF  128.0f              // index = floor(x*INVCW + XOFF)
#define RMAX  6

__device__ __forceinline__ float silu_f(float z) {
    return z / (1.0f + __expf(-z));
}

__device__ __forceinline__ int cell_idx(float v) {
    int i = (int)floorf(fmaf(v, INVCW, XOFF));
    return min(GRID - 1, max(0, i));
}

// ws layout (bytes); cursor aliases counts (counts dead after scanA).
#define WS_MD      0                    // 16384 f   (64 KB)
#define WS_COUNTS  65536                // 65536 i   (256 KB)  == cursor
#define WS_OFFSETS 327680               // 65537 i
#define WS_BSUM    589840               // 64 i
#define WS_BPRE    590096               // 64 i
#define WS_SPTS    590352               // 16384 float2 (128 KB)
#define WS_PIDX    721424               // 16384 i
#define WS_STRAG   786960               // 16384 i
#define WS_NSTRAG  852496               // 1 i        (total ~852.5 KB)

// --- grid build ---------------------------------------------------------
__global__ void k_zero(int* counts, int* nstrag) {
    const int g = blockIdx.x * 256 + threadIdx.x;      // 64x256 -> 16384 int4
    ((int4*)counts)[g] = make_int4(0, 0, 0, 0);
    if (g == 0) *nstrag = 0;
}

__global__ void k_hist(const float* __restrict__ xyf, int* counts) {
    const int i = blockIdx.x * 256 + threadIdx.x;      // 16384
    const float2 p = ((const float2*)xyf)[i];
    const int c = cell_idx(p.y) * GRID + cell_idx(p.x);
    atomicAdd(&counts[c], 1);
}

__global__ __launch_bounds__(256) void k_scanA(const int* __restrict__ counts,
                                               int* offsets, int* bsum) {
    __shared__ int sdata[256];
    const int tid = threadIdx.x;
    const int g   = blockIdx.x * 256 + tid;
    const int4 c4 = ((const int4*)counts)[g];
    const int tsum = c4.x + c4.y + c4.z + c4.w;
    sdata[tid] = tsum;
    __syncthreads();
    for (int off = 1; off < 256; off <<= 1) {
        int v = 0;
        if (tid >= off) v = sdata[tid - off];
        __syncthreads();
        sdata[tid] += v;
        __syncthreads();
    }
    int ex = sdata[tid] - tsum;
    ((int4*)offsets)[g] = make_int4(ex, ex + c4.x, ex + c4.x + c4.y,
                                    ex + c4.x + c4.y + c4.z);
    if (tid == 255) bsum[blockIdx.x] = sdata[255];
}

__global__ void k_scanB(const int* __restrict__ bsum, int* bpre, int* offsets) {
    const int t = threadIdx.x;                         // 64 threads = 1 wave
    const int orig = bsum[t];
    int x = orig;
    for (int off = 1; off < 64; off <<= 1) {
        int y = __shfl_up(x, off, 64);
        if (t >= off) x += y;
    }
    bpre[t] = x - orig;
    if (t == 63) offsets[NCELL] = NPTS;
}

__global__ __launch_bounds__(256) void k_scanC(int* offsets, int* cursor,
                                               const int* __restrict__ bpre) {
    const int g = blockIdx.x * 256 + threadIdx.x;
    const int add = bpre[blockIdx.x];
    int4 o = ((int4*)offsets)[g];
    o.x += add; o.y += add; o.z += add; o.w += add;
    ((int4*)offsets)[g] = o;
    ((int4*)cursor)[g]  = o;
}

__global__ void k_scatter(const float* __restrict__ xyf, int* cursor,
                          float2* spts, int* pidx) {
    const int i = blockIdx.x * 256 + threadIdx.x;      // 16384
    const float2 p = ((const float2*)xyf)[i];
    const int c = cell_idx(p.y) * GRID + cell_idx(p.x);
    const int pos = atomicAdd(&cursor[c], 1);
    spts[pos] = p;
    pidx[pos] = i;
}

// --- phase A: per-thread ring search over SORTED queries ----------------
// Queries processed in cell-sorted order -> lanes of a wave share rings
// (L1 hits, uniform R). Ring rows are contiguous in the sorted array:
// one offsets pair covers a whole row segment.
__device__ __forceinline__ void scan_range(
        const float2* __restrict__ spts, int st, int en, float qx, float qy,
        float& s0, float& s1, float& s2, float& s3, float& s4, float& s5,
        float& s6) {
    for (int p = st; p < en; ++p) {
        const float2 pt = spts[p];
        const float dx = qx - pt.x, dy = qy - pt.y;
        const float d = fmaf(dx, dx, dy * dy);
        if (d < s6) {
            s6 = d; float t;
            if (s6 < s5) { t = s5; s5 = s6; s6 = t; }
            if (s5 < s4) { t = s4; s4 = s5; s5 = t; }
            if (s4 < s3) { t = s3; s3 = s4; s4 = t; }
            if (s3 < s2) { t = s2; s2 = s3; s3 = t; }
            if (s2 < s1) { t = s1; s1 = s2; s2 = t; }
            if (s1 < s0) { t = s0; s0 = s1; s1 = t; }
        }
    }
}

__global__ __launch_bounds__(256) void k_knnA(
        const int* __restrict__ offsets, const float2* __restrict__ spts,
        const int* __restrict__ pidx, float* md, int* nstrag, int* strag) {
    const int j = blockIdx.x * 256 + threadIdx.x;      // sorted query index
    const float2 q = spts[j];
    const int cx = cell_idx(q.x), cy = cell_idx(q.y);

    float s0 = FLT_MAX, s1 = FLT_MAX, s2 = FLT_MAX, s3 = FLT_MAX,
          s4 = FLT_MAX, s5 = FLT_MAX, s6 = FLT_MAX;
    bool done = false;

    for (int R = 0; R <= RMAX && !done; ++R) {
        const int xlo = cx - R, xhi = cx + R, ylo = cy - R, yhi = cy + R;
        const int sx = max(xlo, 0), ex = min(xhi, GRID - 1);
        // top row: full segment (contiguous cells => one point range)
        if (ylo >= 0) {
            const int row = ylo * GRID;
            scan_range(spts, offsets[row + sx], offsets[row + ex + 1],
                       q.x, q.y, s0, s1, s2, s3, s4, s5, s6);
        }
        if (R > 0) {
            // bottom row
            if (yhi <= GRID - 1) {
                const int row = yhi * GRID;
                scan_range(spts, offsets[row + sx], offsets[row + ex + 1],
                           q.x, q.y, s0, s1, s2, s3, s4, s5, s6);
            }
            // interior rows: left/right edge cells only
            const int iy0 = max(ylo + 1, 0), iy1 = min(yhi - 1, GRID - 1);
            for (int iy = iy0; iy <= iy1; ++iy) {
                const int row = iy * GRID;
                if (xlo >= 0)
                    scan_range(spts, offsets[row + xlo], offsets[row + xlo + 1],
                               q.x, q.y, s0, s1, s2, s3, s4, s5, s6);
                if (xhi <= GRID - 1)
                    scan_range(spts, offsets[row + xhi], offsets[row + xhi + 1],
                               q.x, q.y, s0, s1, s2, s3, s4, s5, s6);
            }
        }
        // exact wall bound (clamped edge cells extend to infinity)
        const float bl = (xlo <= 0)        ? FLT_MAX : q.x - (xlo - XOFF) * CELLW;
        const float br = (xhi >= GRID - 1) ? FLT_MAX : (xhi + 1 - XOFF) * CELLW - q.x;
        const float bb = (ylo <= 0)        ? FLT_MAX : q.y - (ylo - XOFF) * CELLW;
        const float bt = (yhi >= GRID - 1) ? FLT_MAX : (yhi + 1 - XOFF) * CELLW - q.y;
        float b = fminf(fminf(bl, br), fminf(bb, bt)) * 0.999999f;
        if (s6 <= b * b) done = true;
    }

    if (done) {
        const float sum = sqrtf(fmaxf(s1, 1e-12f)) + sqrtf(fmaxf(s2, 1e-12f)) +
                          sqrtf(fmaxf(s3, 1e-12f)) + sqrtf(fmaxf(s4, 1e-12f)) +
                          sqrtf(fmaxf(s5, 1e-12f)) + sqrtf(fmaxf(s6, 1e-12f));
        md[pidx[j]] = sum * (1.0f / 6.0f);
    } else {
        const int pos = atomicAdd(nstrag, 1);
        strag[pos] = j;                                // sorted index
    }
}

// --- phase B: wave-per-query brute force for stragglers -----------------
__global__ __launch_bounds__(256) void k_knnB(const float* __restrict__ xyf,
                                              const float2* __restrict__ spts,
                                              const int* __restrict__ pidx,
                                              const int* __restrict__ nstrag,
                                              const int* __restrict__ strag,
                                              float* md) {
    const int lane = threadIdx.x & 63;
    const int wid  = blockIdx.x * 4 + (threadIdx.x >> 6);
    const int nw   = gridDim.x * 4;
    const int n    = *nstrag;
    const float4* xy4 = (const float4*)xyf;

    for (int jj = wid; jj < n; jj += nw) {
        const int j = strag[jj];
        const float2 q = spts[j];
        float t0 = FLT_MAX, t1 = FLT_MAX, t2 = FLT_MAX, t3 = FLT_MAX,
              t4 = FLT_MAX, t5 = FLT_MAX, t6 = FLT_MAX;
        for (int it = 0; it < NPTS / 2 / 64; ++it) {
            const float4 P = xy4[it * 64 + lane];
            float dx, dy, d;
            #pragma unroll
            for (int h = 0; h < 2; ++h) {
                dx = q.x - (h ? P.z : P.x);
                dy = q.y - (h ? P.w : P.y);
                d  = fmaf(dx, dx, dy * dy);
                if (d < t6) {
                    t6 = d; float t;
                    if (t6 < t5) { t = t5; t5 = t6; t6 = t; }
                    if (t5 < t4) { t = t4; t4 = t5; t5 = t; }
                    if (t4 < t3) { t = t3; t3 = t4; t4 = t; }
                    if (t3 < t2) { t = t2; t2 = t3; t3 = t; }
                    if (t2 < t1) { t = t1; t1 = t2; t2 = t; }
                    if (t1 < t0) { t = t0; t0 = t1; t1 = t; }
                }
            }
        }
        float sum = 0.0f;
        #pragma unroll
        for (int r = 0; r < 7; ++r) {
            const float v = t0;
            float m = v;
            #pragma unroll
            for (int o = 32; o; o >>= 1) m = fminf(m, __shfl_xor(m, o, 64));
            const unsigned long long msk = __ballot(v == m);
            if (lane == (__ffsll(msk) - 1)) {
                t0 = t1; t1 = t2; t2 = t3; t3 = t4; t4 = t5; t5 = t6;
                t6 = FLT_MAX;
            }
            if (r > 0) sum += sqrtf(fmaxf(m, 1e-12f));
        }
        if (lane == 0) md[pidx[j]] = sum * (1.0f / 6.0f);
    }
}

// --- fused MLP ----------------------------------------------------------
// 64 points x 256 cols per block, 256 blocks. Thread = 16 pts x 4 cols
// (64 acc). One W-row load (16 B) feeds 64 FMAs -> L2 traffic ~0.4 GB
// (was 3 GB in r5). hA (64 KB LDS) holds g (rows 0..127) for the dist
// GEMM first, then is overwritten with h1 (256 rows) for the main GEMM;
// both GEMMs accumulate into the same registers. All hA reads are
// wave-uniform broadcast b128.
__global__ __launch_bounds__(256) void mlp_kernel(
        const float* __restrict__ xyf,
        const float* __restrict__ W1,  const float* __restrict__ b1,
        const float* __restrict__ W2,  const float* __restrict__ b2,
        const float* __restrict__ Wd1, const float* __restrict__ bd1,
        const float* __restrict__ Wd2, const float* __restrict__ bd2,
        const float* __restrict__ md,  float* __restrict__ out) {
    __shared__ float hA[256 * 64];                    // exactly 64 KB

    const int tid   = threadIdx.x;
    const int lane  = tid & 63;
    const int ty    = tid >> 6;
    const int pbase = blockIdx.x * 64;

    const float2 xp  = ((const float2*)xyf)[pbase + lane];
    const float  mdp = md[pbase + lane];

    // phase D: g[k][p] = silu(md[p]*Wd1[k]+bd1[k]); wave ty does k in [ty*32, ty*32+32)
    #pragma unroll 4
    for (int i = 0; i < 32; ++i) {
        const int k = ty * 32 + i;
        hA[k * 64 + lane] = silu_f(fmaf(mdp, Wd1[k], bd1[k]));
    }
    __syncthreads();

    const int c0 = lane * 4;
    const int p0 = ty * 16;

    float acc[16][4];
    #pragma unroll
    for (int p = 0; p < 16; ++p)
        #pragma unroll
        for (int c = 0; c < 4; ++c) acc[p][c] = 0.0f;

    // dist GEMM: acc += g @ Wd2  (k = 0..127), depth-2 pipelined W loads
    {
        const float* Wc = Wd2 + c0;
        float4 w0 = *(const float4*)(Wc);
        float4 w1 = *(const float4*)(Wc + HDIM);
        for (int k = 0; k < 128; k += 2) {
            const int kn = (k + 2 < 128) ? (k + 2) : 126;
            const float4 n0 = *(const float4*)(Wc + kn * HDIM);
            const float4 n1 = *(const float4*)(Wc + kn * HDIM + HDIM);
            float a0[16], a1[16];
            #pragma unroll
            for (int g4 = 0; g4 < 4; ++g4) {
                const float4 v = *(const float4*)(&hA[k * 64 + p0 + g4 * 4]);
                a0[g4 * 4] = v.x; a0[g4 * 4 + 1] = v.y;
                a0[g4 * 4 + 2] = v.z; a0[g4 * 4 + 3] = v.w;
                const float4 u = *(const float4*)(&hA[(k + 1) * 64 + p0 + g4 * 4]);
                a1[g4 * 4] = u.x; a1[g4 * 4 + 1] = u.y;
                a1[g4 * 4 + 2] = u.z; a1[g4 * 4 + 3] = u.w;
            }
            #pragma unroll
            for (int p = 0; p < 16; ++p) {
                acc[p][0] = fmaf(a0[p], w0.x, acc[p][0]);
                acc[p][1] = fmaf(a0[p], w0.y, acc[p][1]);
                acc[p][2] = fmaf(a0[p], w0.z, acc[p][2]);
                acc[p][3] = fmaf(a0[p], w0.w, acc[p][3]);
            }
            #pragma unroll
            for (int p = 0; p < 16; ++p) {
                acc[p][0] = fmaf(a1[p], w1.x, acc[p][0]);
                acc[p][1] = fmaf(a1[p], w1.y, acc[p][1]);
                acc[p][2] = fmaf(a1[p], w1.z, acc[p][2]);
                acc[p][3] = fmaf(a1[p], w1.w, acc[p][3]);
            }
            w0 = n0; w1 = n1;
        }
    }
    __syncthreads();

    // phase A: h1[k][p] = silu(x[p]@W1[:,k]+b1[k]); wave ty does k in [ty*64,(ty+1)*64)
    #pragma unroll 4
    for (int i = 0; i < 64; ++i) {
        const int k = ty * 64 + i;
        hA[k * 64 + lane] =
            silu_f(fmaf(xp.x, W1[k], fmaf(xp.y, W1[HDIM + k], b1[k])));
    }
    __syncthreads();

    // main GEMM: acc += h1 @ W2  (k = 0..255)
    {
        const float* Wc = W2 + c0;
        float4 w0 = *(const float4*)(Wc);
        float4 w1 = *(const float4*)(Wc + HDIM);
        for (int k = 0; k < 256; k += 2) {
            const int kn = (k + 2 < 256) ? (k + 2) : 254;
            const float4 n0 = *(const float4*)(Wc + kn * HDIM);
            const float4 n1 = *(const float4*)(Wc + kn * HDIM + HDIM);
            float a0[16], a1[16];
            #pragma unroll
            for (int g4 = 0; g4 < 4; ++g4) {
                const float4 v = *(const float4*)(&hA[k * 64 + p0 + g4 * 4]);
                a0[g4 * 4] = v.x; a0[g4 * 4 + 1] = v.y;
                a0[g4 * 4 + 2] = v.z; a0[g4 * 4 + 3] = v.w;
                const float4 u = *(const float4*)(&hA[(k + 1) * 64 + p0 + g4 * 4]);
                a1[g4 * 4] = u.x; a1[g4 * 4 + 1] = u.y;
                a1[g4 * 4 + 2] = u.z; a1[g4 * 4 + 3] = u.w;
            }
            #pragma unroll
            for (int p = 0; p < 16; ++p) {
                acc[p][0] = fmaf(a0[p], w0.x, acc[p][0]);
                acc[p][1] = fmaf(a0[p], w0.y, acc[p][1]);
                acc[p][2] = fmaf(a0[p], w0.z, acc[p][2]);
                acc[p][3] = fmaf(a0[p], w0.w, acc[p][3]);
            }
            #pragma unroll
            for (int p = 0; p < 16; ++p) {
                acc[p][0] = fmaf(a1[p], w1.x, acc[p][0]);
                acc[p][1] = fmaf(a1[p], w1.y, acc[p][1]);
                acc[p][2] = fmaf(a1[p], w1.z, acc[p][2]);
                acc[p][3] = fmaf(a1[p], w1.w, acc[p][3]);
            }
            w0 = n0; w1 = n1;
        }
    }

    // epilogue
    const float4 v2 = *(const float4*)(b2 + c0);
    const float4 vd = *(const float4*)(bd2 + c0);
    #pragma unroll
    for (int p = 0; p < 16; ++p) {
        float4 o;
        o.x = acc[p][0] + v2.x + vd.x;
        o.y = acc[p][1] + v2.y + vd.y;
        o.z = acc[p][2] + v2.z + vd.z;
        o.w = acc[p][3] + v2.w + vd.w;
        *(float4*)(out + (size_t)(pbase + p0 + p) * HDIM + c0) = o;
    }
}

extern "C" void kernel_launch(void* const* d_in, const int* in_sizes, int n_in,
                              void* d_out, int out_size, void* d_ws, size_t ws_size,
                              hipStream_t stream) {
    const float* xy  = (const float*)d_in[0];
    const float* W1  = (const float*)d_in[1];
    const float* b1  = (const float*)d_in[2];
    const float* W2  = (const float*)d_in[3];
    const float* b2  = (const float*)d_in[4];
    const float* Wd1 = (const float*)d_in[5];
    const float* bd1 = (const float*)d_in[6];
    const float* Wd2 = (const float*)d_in[7];
    const float* bd2 = (const float*)d_in[8];
    float* out = (float*)d_out;

    char* ws = (char*)d_ws;
    float*  md      = (float*)(ws + WS_MD);
    int*    counts  = (int*)(ws + WS_COUNTS);   // aliased as cursor after scan
    int*    offsets = (int*)(ws + WS_OFFSETS);
    int*    bsum    = (int*)(ws + WS_BSUM);
    int*    bpre    = (int*)(ws + WS_BPRE);
    float2* spts    = (float2*)(ws + WS_SPTS);
    int*    pidx    = (int*)(ws + WS_PIDX);
    int*    strag   = (int*)(ws + WS_STRAG);
    int*    nstrag  = (int*)(ws + WS_NSTRAG);

    k_zero   <<<64, 256, 0, stream>>>(counts, nstrag);
    k_hist   <<<64, 256, 0, stream>>>(xy, counts);
    k_scanA  <<<64, 256, 0, stream>>>(counts, offsets, bsum);
    k_scanB  <<<1, 64, 0, stream>>>(bsum, bpre, offsets);
    k_scanC  <<<64, 256, 0, stream>>>(offsets, counts /*cursor*/, bpre);
    k_scatter<<<64, 256, 0, stream>>>(xy, counts /*cursor*/, spts, pidx);
    k_knnA   <<<64, 256, 0, stream>>>(offsets, spts, pidx, md, nstrag, strag);
    k_knnB   <<<256, 256, 0, stream>>>(xy, spts, pidx, nstrag, strag, md);
    mlp_kernel<<<NPTS / 64, 256, 0, stream>>>(xy, W1, b1, W2, b2,
                                              Wd1, bd1, Wd2, bd2, md, out);
}

// Round 7
// 244.249 us; speedup vs baseline: 1.3769x; 1.0736x over previous
//
#include <hip/hip_runtime.h>
#include <float.h>
#include <math.h>

#define NPTS  16384
#define HDIM  256
#define GRID  128                 // cells per axis
#define NCELL (GRID * GRID)
#define CELLW 0.78125f            // 100/128
#define INVCW 1.28f
#define XOFF  64.0f               // index = floor(x*INVCW + XOFF)
#define RMAX  8

__device__ __forceinline__ float silu_f(float z) {
    return z / (1.0f + __expf(-z));
}

__device__ __forceinline__ int cell_idx(float v) {
    int i = (int)floorf(fmaf(v, INVCW, XOFF));
    return min(GRID - 1, max(0, i));
}

// ws layout (bytes). counts doubles as cursor (rewritten in k_scan).
// One memset covers counts+nstrag.
#define WS_MD      0               // 16384 f  (64 KB)
#define WS_COUNTS  65536           // 16384 i  (64 KB)  == cursor after scan
#define WS_NSTRAG  131072          // 1 i (pad 16)
#define WS_OFFSETS 131088          // 16385 i
#define WS_SPTS    196640          // 16384 float2 (128 KB)
#define WS_PIDX    327712          // 16384 i
#define WS_STRAG   393248          // 16384 i   (total ~459 KB)

// --- grid build ---------------------------------------------------------
__global__ void k_hist(const float* __restrict__ xyf, int* counts) {
    const int i = blockIdx.x * 256 + threadIdx.x;      // 16384
    const float2 p = ((const float2*)xyf)[i];
    const int c = cell_idx(p.y) * GRID + cell_idx(p.x);
    atomicAdd(&counts[c], 1);
}

// single-block scan of all 16384 cells; writes offsets and rewrites counts
// as the scatter cursor.
__global__ __launch_bounds__(1024) void k_scan(int* counts, int* offsets) {
    __shared__ int wsum[16];
    const int tid  = threadIdx.x;                      // 0..1023
    const int lane = tid & 63, wv = tid >> 6;
    const int base = tid * 16;

    int c[16];
    int tsum = 0;
    #pragma unroll
    for (int i = 0; i < 4; ++i) {
        const int4 v = ((const int4*)counts)[tid * 4 + i];
        c[i * 4 + 0] = v.x; c[i * 4 + 1] = v.y;
        c[i * 4 + 2] = v.z; c[i * 4 + 3] = v.w;
        tsum += v.x + v.y + v.z + v.w;
    }
    int incl = tsum;
    #pragma unroll
    for (int off = 1; off < 64; off <<= 1) {
        const int y = __shfl_up(incl, off, 64);
        if (lane >= off) incl += y;
    }
    if (lane == 63) wsum[wv] = incl;
    __syncthreads();
    int wpre = 0;
    for (int w = 0; w < wv; ++w) wpre += wsum[w];
    int run = wpre + incl - tsum;                      // exclusive start
    #pragma unroll
    for (int i = 0; i < 16; ++i) {
        offsets[base + i] = run;
        counts[base + i]  = run;                       // cursor copy
        run += c[i];
    }
    if (tid == 1023) offsets[NCELL] = NPTS;
}

__global__ void k_scatter(const float* __restrict__ xyf, int* cursor,
                          float2* spts, int* pidx) {
    const int i = blockIdx.x * 256 + threadIdx.x;      // 16384
    const float2 p = ((const float2*)xyf)[i];
    const int c = cell_idx(p.y) * GRID + cell_idx(p.x);
    const int pos = atomicAdd(&cursor[c], 1);
    spts[pos] = p;
    pidx[pos] = i;
}

// --- phase A: per-thread ring search over SORTED queries ----------------
__device__ __forceinline__ void scan_range(
        const float2* __restrict__ spts, int st, int en, float qx, float qy,
        float& s0, float& s1, float& s2, float& s3, float& s4, float& s5,
        float& s6) {
    for (int p = st; p < en; ++p) {
        const float2 pt = spts[p];
        const float dx = qx - pt.x, dy = qy - pt.y;
        const float d = fmaf(dx, dx, dy * dy);
        if (d < s6) {
            s6 = d; float t;
            if (s6 < s5) { t = s5; s5 = s6; s6 = t; }
            if (s5 < s4) { t = s4; s4 = s5; s5 = t; }
            if (s4 < s3) { t = s3; s3 = s4; s4 = t; }
            if (s3 < s2) { t = s2; s2 = s3; s3 = t; }
            if (s2 < s1) { t = s1; s1 = s2; s2 = t; }
            if (s1 < s0) { t = s0; s0 = s1; s1 = t; }
        }
    }
}

__global__ __launch_bounds__(256) void k_knnA(
        const int* __restrict__ offsets, const float2* __restrict__ spts,
        const int* __restrict__ pidx, float* md, int* nstrag, int* strag) {
    const int j = blockIdx.x * 256 + threadIdx.x;      // sorted query index
    const float2 q = spts[j];
    const int cx = cell_idx(q.x), cy = cell_idx(q.y);

    float s0 = FLT_MAX, s1 = FLT_MAX, s2 = FLT_MAX, s3 = FLT_MAX,
          s4 = FLT_MAX, s5 = FLT_MAX, s6 = FLT_MAX;
    bool done = false;

    for (int R = 0; R <= RMAX && !done; ++R) {
        const int xlo = cx - R, xhi = cx + R, ylo = cy - R, yhi = cy + R;
        const int sx = max(xlo, 0), ex = min(xhi, GRID - 1);
        if (ylo >= 0) {                                // top row: one segment
            const int row = ylo * GRID;
            scan_range(spts, offsets[row + sx], offsets[row + ex + 1],
                       q.x, q.y, s0, s1, s2, s3, s4, s5, s6);
        }
        if (R > 0) {
            if (yhi <= GRID - 1) {                     // bottom row
                const int row = yhi * GRID;
                scan_range(spts, offsets[row + sx], offsets[row + ex + 1],
                           q.x, q.y, s0, s1, s2, s3, s4, s5, s6);
            }
            const int iy0 = max(ylo + 1, 0), iy1 = min(yhi - 1, GRID - 1);
            for (int iy = iy0; iy <= iy1; ++iy) {      // side cells
                const int row = iy * GRID;
                if (xlo >= 0)
                    scan_range(spts, offsets[row + xlo], offsets[row + xlo + 1],
                               q.x, q.y, s0, s1, s2, s3, s4, s5, s6);
                if (xhi <= GRID - 1)
                    scan_range(spts, offsets[row + xhi], offsets[row + xhi + 1],
                               q.x, q.y, s0, s1, s2, s3, s4, s5, s6);
            }
        }
        // exact wall bound (clamped edge cells extend to infinity)
        const float bl = (xlo <= 0)        ? FLT_MAX : q.x - (xlo - XOFF) * CELLW;
        const float br = (xhi >= GRID - 1) ? FLT_MAX : (xhi + 1 - XOFF) * CELLW - q.x;
        const float bb = (ylo <= 0)        ? FLT_MAX : q.y - (ylo - XOFF) * CELLW;
        const float bt = (yhi >= GRID - 1) ? FLT_MAX : (yhi + 1 - XOFF) * CELLW - q.y;
        const float b = fminf(fminf(bl, br), fminf(bb, bt)) * 0.999999f;
        if (s6 <= b * b) done = true;
    }

    if (done) {
        const float sum = sqrtf(fmaxf(s1, 1e-12f)) + sqrtf(fmaxf(s2, 1e-12f)) +
                          sqrtf(fmaxf(s3, 1e-12f)) + sqrtf(fmaxf(s4, 1e-12f)) +
                          sqrtf(fmaxf(s5, 1e-12f)) + sqrtf(fmaxf(s6, 1e-12f));
        md[pidx[j]] = sum * (1.0f / 6.0f);
    } else {
        const int pos = atomicAdd(nstrag, 1);
        strag[pos] = j;
    }
}

// --- phase B: wave-per-query brute force for stragglers -----------------
__global__ __launch_bounds__(256) void k_knnB(const float* __restrict__ xyf,
                                              const float2* __restrict__ spts,
                                              const int* __restrict__ pidx,
                                              const int* __restrict__ nstrag,
                                              const int* __restrict__ strag,
                                              float* md) {
    const int lane = threadIdx.x & 63;
    const int wid  = blockIdx.x * 4 + (threadIdx.x >> 6);
    const int nw   = gridDim.x * 4;
    const int n    = *nstrag;
    const float4* xy4 = (const float4*)xyf;

    for (int jj = wid; jj < n; jj += nw) {
        const int j = strag[jj];
        const float2 q = spts[j];
        float t0 = FLT_MAX, t1 = FLT_MAX, t2 = FLT_MAX, t3 = FLT_MAX,
              t4 = FLT_MAX, t5 = FLT_MAX, t6 = FLT_MAX;
        for (int it = 0; it < NPTS / 2 / 64; ++it) {
            const float4 P = xy4[it * 64 + lane];
            float dx, dy, d;
            #pragma unroll
            for (int h = 0; h < 2; ++h) {
                dx = q.x - (h ? P.z : P.x);
                dy = q.y - (h ? P.w : P.y);
                d  = fmaf(dx, dx, dy * dy);
                if (d < t6) {
                    t6 = d; float t;
                    if (t6 < t5) { t = t5; t5 = t6; t6 = t; }
                    if (t5 < t4) { t = t4; t4 = t5; t5 = t; }
                    if (t4 < t3) { t = t3; t3 = t4; t4 = t; }
                    if (t3 < t2) { t = t2; t2 = t3; t3 = t; }
                    if (t2 < t1) { t = t1; t1 = t2; t2 = t; }
                    if (t1 < t0) { t = t0; t0 = t1; t1 = t; }
                }
            }
        }
        float sum = 0.0f;
        #pragma unroll
        for (int r = 0; r < 7; ++r) {
            const float v = t0;
            float m = v;
            #pragma unroll
            for (int o = 32; o; o >>= 1) m = fminf(m, __shfl_xor(m, o, 64));
            const unsigned long long msk = __ballot(v == m);
            if (lane == (__ffsll(msk) - 1)) {
                t0 = t1; t1 = t2; t2 = t3; t3 = t4; t4 = t5; t5 = t6;
                t6 = FLT_MAX;
            }
            if (r > 0) sum += sqrtf(fmaxf(m, 1e-12f));
        }
        if (lane == 0) md[pidx[j]] = sum * (1.0f / 6.0f);
    }
}

// --- fused MLP ----------------------------------------------------------
// 32 points x 256 cols per block, 512 blocks -> 32 KB LDS, 4 blocks/CU,
// 16 waves/CU. Thread = 8 pts x 4 cols (32 acc); one W-row load feeds 32
// FMAs; 4 waves/block share W rows via L1. h-store phase: thread writes
// hA[tid + 256*i] (consecutive addresses -> conflict-free); GEMM reads are
// wave-uniform broadcast b128 at hA[k*32 + p0].
__global__ __launch_bounds__(256, 4) void mlp_kernel(
        const float* __restrict__ xyf,
        const float* __restrict__ W1,  const float* __restrict__ b1,
        const float* __restrict__ W2,  const float* __restrict__ b2,
        const float* __restrict__ Wd1, const float* __restrict__ bd1,
        const float* __restrict__ Wd2, const float* __restrict__ bd2,
        const float* __restrict__ md,  float* __restrict__ out) {
    __shared__ float hA[256 * 32];                    // 32 KB

    const int tid   = threadIdx.x;
    const int pbase = blockIdx.x * 32;
    const int pp    = tid & 31;                        // point for store phase
    const int kg    = tid >> 5;                        // k-group 0..7

    const float2 xp  = ((const float2*)xyf)[pbase + pp];
    const float  mdp = md[pbase + pp];

    // phase D: g[k][p] = silu(md[p]*Wd1[k]+bd1[k]), k = kg + 8*i, i<16
    #pragma unroll 4
    for (int i = 0; i < 16; ++i) {
        const int k = kg + 8 * i;
        hA[tid + 256 * i] = silu_f(fmaf(mdp, Wd1[k], bd1[k]));
    }
    __syncthreads();

    const int tx = tid & 63;
    const int ty = tid >> 6;
    const int c0 = tx * 4;
    const int p0 = ty * 8;

    float acc[8][4];
    #pragma unroll
    for (int p = 0; p < 8; ++p)
        #pragma unroll
        for (int c = 0; c < 4; ++c) acc[p][c] = 0.0f;

    // dist GEMM: acc += g @ Wd2 (k = 0..127), depth-2 pipelined W loads
    {
        const float* Wc = Wd2 + c0;
        float4 w0 = *(const float4*)(Wc);
        float4 w1 = *(const float4*)(Wc + HDIM);
        for (int k = 0; k < 128; k += 2) {
            const int kn = (k + 2 < 128) ? (k + 2) : 126;
            const float4 n0 = *(const float4*)(Wc + kn * HDIM);
            const float4 n1 = *(const float4*)(Wc + kn * HDIM + HDIM);
            const float4 a0 = *(const float4*)(&hA[k * 32 + p0]);
            const float4 a1 = *(const float4*)(&hA[k * 32 + p0 + 4]);
            const float4 b0 = *(const float4*)(&hA[(k + 1) * 32 + p0]);
            const float4 b1v = *(const float4*)(&hA[(k + 1) * 32 + p0 + 4]);
            const float ak[8] = {a0.x, a0.y, a0.z, a0.w, a1.x, a1.y, a1.z, a1.w};
            const float al[8] = {b0.x, b0.y, b0.z, b0.w, b1v.x, b1v.y, b1v.z, b1v.w};
            #pragma unroll
            for (int p = 0; p < 8; ++p) {
                acc[p][0] = fmaf(ak[p], w0.x, acc[p][0]);
                acc[p][1] = fmaf(ak[p], w0.y, acc[p][1]);
                acc[p][2] = fmaf(ak[p], w0.z, acc[p][2]);
                acc[p][3] = fmaf(ak[p], w0.w, acc[p][3]);
            }
            #pragma unroll
            for (int p = 0; p < 8; ++p) {
                acc[p][0] = fmaf(al[p], w1.x, acc[p][0]);
                acc[p][1] = fmaf(al[p], w1.y, acc[p][1]);
                acc[p][2] = fmaf(al[p], w1.z, acc[p][2]);
                acc[p][3] = fmaf(al[p], w1.w, acc[p][3]);
            }
            w0 = n0; w1 = n1;
        }
    }
    __syncthreads();

    // phase A: h1[k][p] = silu(x[p]@W1[:,k]+b1[k]), k = kg + 8*i, i<32
    #pragma unroll 4
    for (int i = 0; i < 32; ++i) {
        const int k = kg + 8 * i;
        hA[tid + 256 * i] =
            silu_f(fmaf(xp.x, W1[k], fmaf(xp.y, W1[HDIM + k], b1[k])));
    }
    __syncthreads();

    // main GEMM: acc += h1 @ W2 (k = 0..255)
    {
        const float* Wc = W2 + c0;
        float4 w0 = *(const float4*)(Wc);
        float4 w1 = *(const float4*)(Wc + HDIM);
        for (int k = 0; k < 256; k += 2) {
            const int kn = (k + 2 < 256) ? (k + 2) : 254;
            const float4 n0 = *(const float4*)(Wc + kn * HDIM);
            const float4 n1 = *(const float4*)(Wc + kn * HDIM + HDIM);
            const float4 a0 = *(const float4*)(&hA[k * 32 + p0]);
            const float4 a1 = *(const float4*)(&hA[k * 32 + p0 + 4]);
            const float4 b0 = *(const float4*)(&hA[(k + 1) * 32 + p0]);
            const float4 b1v = *(const float4*)(&hA[(k + 1) * 32 + p0 + 4]);
            const float ak[8] = {a0.x, a0.y, a0.z, a0.w, a1.x, a1.y, a1.z, a1.w};
            const float al[8] = {b0.x, b0.y, b0.z, b0.w, b1v.x, b1v.y, b1v.z, b1v.w};
            #pragma unroll
            for (int p = 0; p < 8; ++p) {
                acc[p][0] = fmaf(ak[p], w0.x, acc[p][0]);
                acc[p][1] = fmaf(ak[p], w0.y, acc[p][1]);
                acc[p][2] = fmaf(ak[p], w0.z, acc[p][2]);
                acc[p][3] = fmaf(ak[p], w0.w, acc[p][3]);
            }
            #pragma unroll
            for (int p = 0; p < 8; ++p) {
                acc[p][0] = fmaf(al[p], w1.x, acc[p][0]);
                acc[p][1] = fmaf(al[p], w1.y, acc[p][1]);
                acc[p][2] = fmaf(al[p], w1.z, acc[p][2]);
                acc[p][3] = fmaf(al[p], w1.w, acc[p][3]);
            }
            w0 = n0; w1 = n1;
        }
    }

    // epilogue
    const float4 v2 = *(const float4*)(b2 + c0);
    const float4 vd = *(const float4*)(bd2 + c0);
    #pragma unroll
    for (int p = 0; p < 8; ++p) {
        float4 o;
        o.x = acc[p][0] + v2.x + vd.x;
        o.y = acc[p][1] + v2.y + vd.y;
        o.z = acc[p][2] + v2.z + vd.z;
        o.w = acc[p][3] + v2.w + vd.w;
        *(float4*)(out + (size_t)(pbase + p0 + p) * HDIM + c0) = o;
    }
}

extern "C" void kernel_launch(void* const* d_in, const int* in_sizes, int n_in,
                              void* d_out, int out_size, void* d_ws, size_t ws_size,
                              hipStream_t stream) {
    const float* xy  = (const float*)d_in[0];
    const float* W1  = (const float*)d_in[1];
    const float* b1  = (const float*)d_in[2];
    const float* W2  = (const float*)d_in[3];
    const float* b2  = (const float*)d_in[4];
    const float* Wd1 = (const float*)d_in[5];
    const float* bd1 = (const float*)d_in[6];
    const float* Wd2 = (const float*)d_in[7];
    const float* bd2 = (const float*)d_in[8];
    float* out = (float*)d_out;

    char* ws = (char*)d_ws;
    float*  md      = (float*)(ws + WS_MD);
    int*    counts  = (int*)(ws + WS_COUNTS);   // cursor after k_scan
    int*    nstrag  = (int*)(ws + WS_NSTRAG);
    int*    offsets = (int*)(ws + WS_OFFSETS);
    float2* spts    = (float2*)(ws + WS_SPTS);
    int*    pidx    = (int*)(ws + WS_PIDX);
    int*    strag   = (int*)(ws + WS_STRAG);

    hipMemsetAsync(counts, 0, 16384 * 4 + 16, stream);   // counts + nstrag
    k_hist   <<<64, 256, 0, stream>>>(xy, counts);
    k_scan   <<<1, 1024, 0, stream>>>(counts, offsets);
    k_scatter<<<64, 256, 0, stream>>>(xy, counts /*cursor*/, spts, pidx);
    k_knnA   <<<64, 256, 0, stream>>>(offsets, spts, pidx, md, nstrag, strag);
    k_knnB   <<<256, 256, 0, stream>>>(xy, spts, pidx, nstrag, strag, md);
    mlp_kernel<<<NPTS / 32, 256, 0, stream>>>(xy, W1, b1, W2, b2,
                                              Wd1, bd1, Wd2, bd2, md, out);
}